// Round 5
// baseline (212.819 us; speedup 1.0000x reference)
//
#include <hip/hip_runtime.h>
#include <math.h>

// GCN collapsed to scalar-per-node form:
//   deg[c] = 1 + #{col==c};  dinv = rsqrt(deg);  u = dinv*x
//   s_raw[c] = sum_{col=c} u[row];  sc = dinv*s_raw + dinv^2*x
//   w_raw[r] = sum_{row=r} dinv[col];  w = dinv*(w_raw + dinv)
//   total[k] = sum_i w[i]*relu(sc[i]*W1[k]+b1[k]);  out = total/N @ W2 + b2
//
// R10: deg-histogram subsystem deleted. deg[] is now computed by
// fire-and-forget global atomicAdd during scatter (1.6M non-returning
// atomics over 400KB -- negligible contention, hidden under scatter's
// existing traffic). Replaces hist_deg (600 blocks, 9.8MB partial write)
// + the 24-strided-stream finalize_deg read. 6 -> 5 launches, -19.6MB.
// curC/curR now hold COUNTS (base b*CAP implicit) so init is simpler.
// hist_gather_both: 512 threads/block (18.8 waves/CU) for gather-latency
// hiding. Kept: rtn-atomic scatter, tslot de-contended accumulator,
// fence-free ticket epilogue (all cross-block traffic = device atomics).

constexpr int BKT_BITS = 12;
constexpr int BKT_SIZE = 1 << BKT_BITS;   // 4096
constexpr int NBMAX    = 32;
constexpr int CAP      = 67584;           // per-bucket region capacity (mean+8sigma)
constexpr int SLICES   = 12;              // gather-hist slices per bucket
constexpr int EPT      = 8;               // edges per thread in scatter
constexpr int NSLOT    = 32;              // accumulator slot-groups

__global__ void init_misc(int* __restrict__ curC, int* __restrict__ curR,
                          float* __restrict__ tslot, unsigned* __restrict__ cnt,
                          unsigned* __restrict__ deg, int N) {
    int t = blockIdx.x * blockDim.x + threadIdx.x;
    if (t < NBMAX) { curC[t] = 0; curR[t] = 0; }
    if (t < NSLOT * 128) tslot[t] = 0.0f;
    if (t == NSLOT * 128) *cnt = 0u;
    for (int i = t; i < N; i += gridDim.x * blockDim.x) deg[i] = 0u;
}

// One tile (2048 edges) per block. Single return-atomic per edge-side gives
// the within-tile slot; global range reserved once per bucket after sync.
// deg[] accumulated via non-returning global atomics (fire-and-forget).
__global__ void scatter_edges(const int* __restrict__ row, const int* __restrict__ col,
                              int* __restrict__ SC, int* __restrict__ SR,
                              int* __restrict__ curC, int* __restrict__ curR,
                              unsigned* __restrict__ deg, int E) {
    __shared__ int hC[NBMAX], hR[NBMAX], bC[NBMAX], bR[NBMAX];
    const int TILE = blockDim.x * EPT;
    const int myBase = blockIdx.x * TILE + threadIdx.x * EPT;
    int r[EPT], c[EPT];
    if (myBase + EPT <= E) {
        int4 r0 = *reinterpret_cast<const int4*>(row + myBase);
        int4 r1 = *reinterpret_cast<const int4*>(row + myBase + 4);
        int4 c0 = *reinterpret_cast<const int4*>(col + myBase);
        int4 c1 = *reinterpret_cast<const int4*>(col + myBase + 4);
        r[0]=r0.x; r[1]=r0.y; r[2]=r0.z; r[3]=r0.w;
        r[4]=r1.x; r[5]=r1.y; r[6]=r1.z; r[7]=r1.w;
        c[0]=c0.x; c[1]=c0.y; c[2]=c0.z; c[3]=c0.w;
        c[4]=c1.x; c[5]=c1.y; c[6]=c1.z; c[7]=c1.w;
    } else {
#pragma unroll
        for (int j = 0; j < EPT; ++j) {
            int e = myBase + j;
            r[j] = (e < E) ? row[e] : -1;
            c[j] = (e < E) ? col[e] : -1;
        }
    }
    if (threadIdx.x < NBMAX) { hC[threadIdx.x] = 0; hR[threadIdx.x] = 0; }
    __syncthreads();
    int offC[EPT], offR[EPT];
#pragma unroll
    for (int j = 0; j < EPT; ++j) {
        if (r[j] >= 0) {
            atomicAdd(&deg[c[j]], 1u);                       // fire-and-forget
            offC[j] = atomicAdd(&hC[c[j] >> BKT_BITS], 1);   // rtn-atomic: slot
            offR[j] = atomicAdd(&hR[r[j] >> BKT_BITS], 1);
        }
    }
    __syncthreads();
    if (threadIdx.x < NBMAX) {
        bC[threadIdx.x] = atomicAdd(&curC[threadIdx.x], hC[threadIdx.x]);
        bR[threadIdx.x] = atomicAdd(&curR[threadIdx.x], hR[threadIdx.x]);
    }
    __syncthreads();
#pragma unroll
    for (int j = 0; j < EPT; ++j) {
        if (r[j] >= 0) {
            int kb = c[j] >> BKT_BITS;
            int idx = kb * CAP + bC[kb] + offC[j];
            if (idx < (kb + 1) * CAP)           // overflow clamp (8-sigma margin)
                SC[idx] = ((c[j] & (BKT_SIZE - 1)) << 17) | r[j];
            int kb2 = r[j] >> BKT_BITS;
            int idx2 = kb2 * CAP + bR[kb2] + offR[j];
            if (idx2 < (kb2 + 1) * CAP)
                SR[idx2] = ((r[j] & (BKT_SIZE - 1)) << 17) | c[j];
        }
    }
}

__global__ void finalize_deg(const unsigned* __restrict__ deg, const float* __restrict__ x,
                             float* __restrict__ dinv, float* __restrict__ u, int N) {
    int i = blockIdx.x * blockDim.x + threadIdx.x;
    if (i >= N) return;
    float d = 1.0f + (float)deg[i];   // +1 = self loop
    float di = rsqrtf(d);
    dinv[i] = di;
    u[i] = di * x[i];
}

// first half of grid: s-hist over SC gathering u; second half: w-hist over SR
// gathering dinv. Branch is block-uniform. 512 threads for latency hiding.
__global__ void hist_gather_both(const int* __restrict__ SC, const int* __restrict__ SR,
                                 const int* __restrict__ curC, const int* __restrict__ curR,
                                 const float* __restrict__ u, const float* __restrict__ dinv,
                                 float* __restrict__ Ps, float* __restrict__ Pw,
                                 int stride, int half) {
    __shared__ float bins[BKT_SIZE];
    const bool isW = blockIdx.x >= half;
    const int id = isW ? blockIdx.x - half : blockIdx.x;
    const int* S = isW ? SR : SC;
    const int* cur = isW ? curR : curC;
    const float* val = isW ? dinv : u;
    float* P = isW ? Pw : Ps;
    const int b = id / SLICES, s = id % SLICES;
    const int base = b * CAP;
    int len = cur[b];
    len = len < CAP ? len : CAP;
    const int lo = base + (int)((long long)len * s / SLICES);
    const int hi = base + (int)((long long)len * (s + 1) / SLICES);
    for (int i = threadIdx.x; i < BKT_SIZE; i += blockDim.x) bins[i] = 0.0f;
    __syncthreads();
    for (int e = lo + threadIdx.x; e < hi; e += blockDim.x) {
        int v = S[e];
        atomicAdd(&bins[v >> 17], val[v & 0x1FFFF]);
    }
    __syncthreads();
    float* dst = P + (size_t)s * stride + b * BKT_SIZE;
    for (int i = threadIdx.x; i < BKT_SIZE; i += blockDim.x) dst[i] = bins[i];
}

// Fused: finalize sc/w for 256 nodes, per-block k-phase from LDS broadcasts,
// atomic-accumulate into tslot[blockIdx&31][128]; LAST block (device-scope
// ticket) sums the 32x128 slots and runs the 128x400 W2 epilogue inline.
__global__ void fused_node(const float* __restrict__ Ps, const float* __restrict__ Pw,
                           const float* __restrict__ dinv, const float* __restrict__ x,
                           const float* __restrict__ W1, const float* __restrict__ b1,
                           float* __restrict__ tslot, int N, int stride,
                           const float* __restrict__ W2, const float* __restrict__ b2,
                           float* __restrict__ out, int OUT, float invN,
                           unsigned* __restrict__ cnt) {
    __shared__ float scs[256];
    __shared__ float ws[256];
    __shared__ float red[256];
    __shared__ unsigned lastFlag;
    const int tid = threadIdx.x;
    const int i = blockIdx.x * 256 + tid;
    float scv = 0.0f, wv = 0.0f;
    if (i < N) {
        float sr = 0.0f, wr = 0.0f;
        for (int s = 0; s < SLICES; ++s) {
            sr += Ps[(size_t)s * stride + i];
            wr += Pw[(size_t)s * stride + i];
        }
        float di = dinv[i];
        scv = di * sr + di * di * x[i];
        wv  = di * (wr + di);
    }
    scs[tid] = scv;
    ws[tid]  = wv;     // 0 for i>=N -> zero contribution
    __syncthreads();
    const int k = tid & 127;
    const int base = (tid >> 7) * 128;
    const float w1k = W1[k];
    const float b1k = b1[k];
    float acc = 0.0f;
#pragma unroll 4
    for (int j = 0; j < 128; ++j) {
        float h = scs[base + j] * w1k + b1k;
        h = h > 0.0f ? h : 0.0f;
        acc += ws[base + j] * h;
    }
    red[tid] = acc;
    __syncthreads();
    if (tid < 128)
        atomicAdd(&tslot[(blockIdx.x & (NSLOT - 1)) * 128 + k],
                  red[tid] + red[tid + 128]);
    // __syncthreads below drains vmcnt -> this block's tslot atomics are
    // acked at the coherence point before its ticket increments. No fence:
    // all cross-block traffic here is device-scope atomics.
    __syncthreads();
    if (tid == 0)
        lastFlag = (atomicAdd(cnt, 1u) == (unsigned)(gridDim.x - 1)) ? 1u : 0u;
    __syncthreads();
    if (lastFlag) {
        __shared__ float tv[128];
        if (tid < 128) {
            float s = 0.0f;
#pragma unroll
            for (int g = 0; g < NSLOT; ++g)
                s += atomicAdd(&tslot[g * 128 + tid], 0.0f);  // coherent reads
            tv[tid] = s * invN;
        }
        __syncthreads();
        for (int d = tid; d < OUT; d += 256) {
            float a = b2[d];
#pragma unroll 4
            for (int kk = 0; kk < 128; ++kk) a += tv[kk] * W2[kk * OUT + d];
            out[d] = a;
        }
    }
}

extern "C" void kernel_launch(void* const* d_in, const int* in_sizes, int n_in,
                              void* d_out, int out_size, void* d_ws, size_t ws_size,
                              hipStream_t stream) {
    const float* x          = (const float*)d_in[0];
    const int*   edge_index = (const int*)  d_in[1];
    const float* W1         = (const float*)d_in[2];
    const float* b1         = (const float*)d_in[3];
    const float* W2         = (const float*)d_in[4];
    const float* b2         = (const float*)d_in[5];
    float* out = (float*)d_out;

    const int N   = in_sizes[0];      // 100000
    const int E   = in_sizes[1] / 2;  // 1600000
    const int OUT = in_sizes[5];      // 400

    const int* row = edge_index;
    const int* col = edge_index + E;

    const int NB = (N + BKT_SIZE - 1) >> BKT_BITS;   // 25
    const int stride = NB * BKT_SIZE;                // 102400

    // workspace layout
    char* p = (char*)d_ws;
    float* dinv  = (float*)p; p += (size_t)N * 4;
    float* u     = (float*)p; p += (size_t)N * 4;
    float* tslot = (float*)p; p += (size_t)NSLOT * 128 * 4;   // 16 KB
    int*   ints  = (int*)p;   p += 512;              // 128 ints: curC|curR|cnt
    unsigned* deg = (unsigned*)p; p += (size_t)N * 4;
    int*   SC    = (int*)p;   p += (size_t)NB * CAP * 4;
    int*   SR    = (int*)p;   p += (size_t)NB * CAP * 4;
    float* P     = (float*)p;                        // 2*SLICES*stride floats
    float* Ps    = P;
    float* Pw    = P + (size_t)SLICES * stride;

    int* curC = ints;
    int* curR = ints + 32;
    unsigned* cnt = (unsigned*)(ints + 64);

    const int TILE   = 256 * EPT;
    const int nTiles = (E + TILE - 1) / TILE;        // 782 -> one tile per block

    init_misc<<<64, 256, 0, stream>>>(curC, curR, tslot, cnt, deg, N);
    scatter_edges<<<nTiles, 256, 0, stream>>>(row, col, SC, SR, curC, curR, deg, E);
    finalize_deg<<<(N + 255) / 256, 256, 0, stream>>>(deg, x, dinv, u, N);
    const int half = NB * SLICES;
    hist_gather_both<<<2 * half, 512, 0, stream>>>(SC, SR, curC, curR, u, dinv,
                                                   Ps, Pw, stride, half);
    fused_node<<<(N + 255) / 256, 256, 0, stream>>>(Ps, Pw, dinv, x, W1, b1,
                                                    tslot, N, stride,
                                                    W2, b2, out, OUT,
                                                    1.0f / (float)N, cnt);
}

// Round 6
// 197.922 us; speedup vs baseline: 1.0753x; 1.0753x over previous
//
#include <hip/hip_runtime.h>
#include <math.h>

// GCN collapsed to scalar-per-node form:
//   deg[c] = 1 + #{col==c};  dinv = rsqrt(deg);  u = dinv*x
//   s_raw[c] = sum_{col=c} u[row];  sc = dinv*s_raw + dinv^2*x
//   w_raw[r] = sum_{row=r} dinv[col];  w = dinv*(w_raw + dinv)
//   total[k] = sum_i w[i]*relu(sc[i]*W1[k]+b1[k]);  out = total/N @ W2 + b2
//
// R11: R10's fire-and-forget global deg atomics were a measured -36us
// regression (scatter 85.7us, +50MB dirty-line writeback from 1.6M
// random-line L2 RMWs). Reverted to sliced hist_deg partials. Model
// refinements applied: (a) LDS-atomic histogram time is fixed per-CU, so
// slices only need to COVER 256 CUs -- S_D 24->12, gather SLICES 12->6
// (halves both partial round-trips, 19.6MB -> 9.8MB total). (b) scatter
// was grid-limited (occ 28% == 782 blocks = 12 waves/CU, all pipes idle):
// EPT 8->4 -> 1563 blocks = 24 waves/CU for LDS-atomic latency hiding.
// Kept: rtn-atomic scatter, count-semantics curC/curR, tslot de-contended
// accumulator, fence-free ticket epilogue.

constexpr int BKT_BITS = 12;
constexpr int BKT_SIZE = 1 << BKT_BITS;   // 4096
constexpr int NBMAX    = 32;
constexpr int CAP      = 67584;           // per-bucket region capacity (mean+8sigma)
constexpr int SLICES   = 6;               // gather-hist slices per bucket
constexpr int SLICES_D = 12;              // deg-hist slices per bucket
constexpr int EPT      = 4;               // edges per thread in scatter
constexpr int NSLOT    = 32;              // accumulator slot-groups

__global__ void init_misc(int* __restrict__ curC, int* __restrict__ curR,
                          float* __restrict__ tslot, unsigned* __restrict__ cnt) {
    int t = threadIdx.x;
    if (t < NBMAX) { curC[t] = 0; curR[t] = 0; }
    for (int j = t; j < NSLOT * 128; j += 256) tslot[j] = 0.0f;
    if (t == 0) *cnt = 0u;
}

// One tile (1024 edges) per block. Single return-atomic per edge-side gives
// the within-tile slot; global range reserved once per bucket after sync.
__global__ void scatter_edges(const int* __restrict__ row, const int* __restrict__ col,
                              int* __restrict__ SC, int* __restrict__ SR,
                              int* __restrict__ curC, int* __restrict__ curR, int E) {
    __shared__ int hC[NBMAX], hR[NBMAX], bC[NBMAX], bR[NBMAX];
    const int TILE = blockDim.x * EPT;
    const int myBase = blockIdx.x * TILE + threadIdx.x * EPT;
    int r[EPT], c[EPT];
    if (myBase + EPT <= E) {
        int4 r0 = *reinterpret_cast<const int4*>(row + myBase);
        int4 c0 = *reinterpret_cast<const int4*>(col + myBase);
        r[0]=r0.x; r[1]=r0.y; r[2]=r0.z; r[3]=r0.w;
        c[0]=c0.x; c[1]=c0.y; c[2]=c0.z; c[3]=c0.w;
    } else {
#pragma unroll
        for (int j = 0; j < EPT; ++j) {
            int e = myBase + j;
            r[j] = (e < E) ? row[e] : -1;
            c[j] = (e < E) ? col[e] : -1;
        }
    }
    if (threadIdx.x < NBMAX) { hC[threadIdx.x] = 0; hR[threadIdx.x] = 0; }
    __syncthreads();
    int offC[EPT], offR[EPT];
#pragma unroll
    for (int j = 0; j < EPT; ++j) {
        if (r[j] >= 0) {
            offC[j] = atomicAdd(&hC[c[j] >> BKT_BITS], 1);   // rtn-atomic: slot
            offR[j] = atomicAdd(&hR[r[j] >> BKT_BITS], 1);
        }
    }
    __syncthreads();
    if (threadIdx.x < NBMAX) {
        bC[threadIdx.x] = atomicAdd(&curC[threadIdx.x], hC[threadIdx.x]);
        bR[threadIdx.x] = atomicAdd(&curR[threadIdx.x], hR[threadIdx.x]);
    }
    __syncthreads();
#pragma unroll
    for (int j = 0; j < EPT; ++j) {
        if (r[j] >= 0) {
            int kb = c[j] >> BKT_BITS;
            int idx = kb * CAP + bC[kb] + offC[j];
            if (idx < (kb + 1) * CAP)           // overflow clamp (8-sigma margin)
                SC[idx] = ((c[j] & (BKT_SIZE - 1)) << 17) | r[j];
            int kb2 = r[j] >> BKT_BITS;
            int idx2 = kb2 * CAP + bR[kb2] + offR[j];
            if (idx2 < (kb2 + 1) * CAP)
                SR[idx2] = ((r[j] & (BKT_SIZE - 1)) << 17) | c[j];
        }
    }
}

__global__ void hist_deg(const int* __restrict__ SC, const int* __restrict__ cur,
                         float* __restrict__ P, int stride) {
    __shared__ float bins[BKT_SIZE];
    const int b = blockIdx.x / SLICES_D, s = blockIdx.x % SLICES_D;
    const int base = b * CAP;
    int len = cur[b];
    len = len < CAP ? len : CAP;
    const int lo = base + (int)((long long)len * s / SLICES_D);
    const int hi = base + (int)((long long)len * (s + 1) / SLICES_D);
    for (int i = threadIdx.x; i < BKT_SIZE; i += blockDim.x) bins[i] = 0.0f;
    __syncthreads();
    for (int e = lo + threadIdx.x; e < hi; e += blockDim.x)
        atomicAdd(&bins[SC[e] >> 17], 1.0f);
    __syncthreads();
    float* dst = P + (size_t)s * stride + b * BKT_SIZE;
    for (int i = threadIdx.x; i < BKT_SIZE; i += blockDim.x) dst[i] = bins[i];
}

__global__ void finalize_deg(const float* __restrict__ Pd, const float* __restrict__ x,
                             float* __restrict__ dinv, float* __restrict__ u,
                             int N, int stride) {
    int i = blockIdx.x * blockDim.x + threadIdx.x;
    if (i >= N) return;
    float d = 1.0f;  // self loop
    for (int s = 0; s < SLICES_D; ++s) d += Pd[(size_t)s * stride + i];
    float di = rsqrtf(d);
    dinv[i] = di;
    u[i] = di * x[i];
}

// first half of grid: s-hist over SC gathering u; second half: w-hist over SR
// gathering dinv. Branch is block-uniform. 512 threads for latency hiding.
__global__ void hist_gather_both(const int* __restrict__ SC, const int* __restrict__ SR,
                                 const int* __restrict__ curC, const int* __restrict__ curR,
                                 const float* __restrict__ u, const float* __restrict__ dinv,
                                 float* __restrict__ Ps, float* __restrict__ Pw,
                                 int stride, int half) {
    __shared__ float bins[BKT_SIZE];
    const bool isW = blockIdx.x >= half;
    const int id = isW ? blockIdx.x - half : blockIdx.x;
    const int* S = isW ? SR : SC;
    const int* cur = isW ? curR : curC;
    const float* val = isW ? dinv : u;
    float* P = isW ? Pw : Ps;
    const int b = id / SLICES, s = id % SLICES;
    const int base = b * CAP;
    int len = cur[b];
    len = len < CAP ? len : CAP;
    const int lo = base + (int)((long long)len * s / SLICES);
    const int hi = base + (int)((long long)len * (s + 1) / SLICES);
    for (int i = threadIdx.x; i < BKT_SIZE; i += blockDim.x) bins[i] = 0.0f;
    __syncthreads();
    for (int e = lo + threadIdx.x; e < hi; e += blockDim.x) {
        int v = S[e];
        atomicAdd(&bins[v >> 17], val[v & 0x1FFFF]);
    }
    __syncthreads();
    float* dst = P + (size_t)s * stride + b * BKT_SIZE;
    for (int i = threadIdx.x; i < BKT_SIZE; i += blockDim.x) dst[i] = bins[i];
}

// Fused: finalize sc/w for 256 nodes, per-block k-phase from LDS broadcasts,
// atomic-accumulate into tslot[blockIdx&31][128]; LAST block (device-scope
// ticket) sums the 32x128 slots and runs the 128x400 W2 epilogue inline.
__global__ void fused_node(const float* __restrict__ Ps, const float* __restrict__ Pw,
                           const float* __restrict__ dinv, const float* __restrict__ x,
                           const float* __restrict__ W1, const float* __restrict__ b1,
                           float* __restrict__ tslot, int N, int stride,
                           const float* __restrict__ W2, const float* __restrict__ b2,
                           float* __restrict__ out, int OUT, float invN,
                           unsigned* __restrict__ cnt) {
    __shared__ float scs[256];
    __shared__ float ws[256];
    __shared__ float red[256];
    __shared__ unsigned lastFlag;
    const int tid = threadIdx.x;
    const int i = blockIdx.x * 256 + tid;
    float scv = 0.0f, wv = 0.0f;
    if (i < N) {
        float sr = 0.0f, wr = 0.0f;
        for (int s = 0; s < SLICES; ++s) {
            sr += Ps[(size_t)s * stride + i];
            wr += Pw[(size_t)s * stride + i];
        }
        float di = dinv[i];
        scv = di * sr + di * di * x[i];
        wv  = di * (wr + di);
    }
    scs[tid] = scv;
    ws[tid]  = wv;     // 0 for i>=N -> zero contribution
    __syncthreads();
    const int k = tid & 127;
    const int base = (tid >> 7) * 128;
    const float w1k = W1[k];
    const float b1k = b1[k];
    float acc = 0.0f;
#pragma unroll 4
    for (int j = 0; j < 128; ++j) {
        float h = scs[base + j] * w1k + b1k;
        h = h > 0.0f ? h : 0.0f;
        acc += ws[base + j] * h;
    }
    red[tid] = acc;
    __syncthreads();
    if (tid < 128)
        atomicAdd(&tslot[(blockIdx.x & (NSLOT - 1)) * 128 + k],
                  red[tid] + red[tid + 128]);
    // __syncthreads below drains vmcnt -> this block's tslot atomics are
    // acked at the coherence point before its ticket increments. No fence:
    // all cross-block traffic here is device-scope atomics.
    __syncthreads();
    if (tid == 0)
        lastFlag = (atomicAdd(cnt, 1u) == (unsigned)(gridDim.x - 1)) ? 1u : 0u;
    __syncthreads();
    if (lastFlag) {
        __shared__ float tv[128];
        if (tid < 128) {
            float s = 0.0f;
#pragma unroll
            for (int g = 0; g < NSLOT; ++g)
                s += atomicAdd(&tslot[g * 128 + tid], 0.0f);  // coherent reads
            tv[tid] = s * invN;
        }
        __syncthreads();
        for (int d = tid; d < OUT; d += 256) {
            float a = b2[d];
#pragma unroll 4
            for (int kk = 0; kk < 128; ++kk) a += tv[kk] * W2[kk * OUT + d];
            out[d] = a;
        }
    }
}

extern "C" void kernel_launch(void* const* d_in, const int* in_sizes, int n_in,
                              void* d_out, int out_size, void* d_ws, size_t ws_size,
                              hipStream_t stream) {
    const float* x          = (const float*)d_in[0];
    const int*   edge_index = (const int*)  d_in[1];
    const float* W1         = (const float*)d_in[2];
    const float* b1         = (const float*)d_in[3];
    const float* W2         = (const float*)d_in[4];
    const float* b2         = (const float*)d_in[5];
    float* out = (float*)d_out;

    const int N   = in_sizes[0];      // 100000
    const int E   = in_sizes[1] / 2;  // 1600000
    const int OUT = in_sizes[5];      // 400

    const int* row = edge_index;
    const int* col = edge_index + E;

    const int NB = (N + BKT_SIZE - 1) >> BKT_BITS;   // 25
    const int stride = NB * BKT_SIZE;                // 102400

    // workspace layout
    char* p = (char*)d_ws;
    float* dinv  = (float*)p; p += (size_t)N * 4;
    float* u     = (float*)p; p += (size_t)N * 4;
    float* tslot = (float*)p; p += (size_t)NSLOT * 128 * 4;   // 16 KB
    int*   ints  = (int*)p;   p += 512;              // 128 ints: curC|curR|cnt
    int*   SC    = (int*)p;   p += (size_t)NB * CAP * 4;
    int*   SR    = (int*)p;   p += (size_t)NB * CAP * 4;
    float* P     = (float*)p;                        // max(SLICES_D, 2*SLICES)*stride
    float* Ps    = P;                                // aliases Pd (sequential phases)
    float* Pw    = P + (size_t)SLICES * stride;

    int* curC = ints;
    int* curR = ints + 32;
    unsigned* cnt = (unsigned*)(ints + 64);

    const int TILE   = 256 * EPT;
    const int nTiles = (E + TILE - 1) / TILE;        // 1563 -> 6 blocks/CU

    init_misc<<<1, 256, 0, stream>>>(curC, curR, tslot, cnt);
    scatter_edges<<<nTiles, 256, 0, stream>>>(row, col, SC, SR, curC, curR, E);
    hist_deg<<<NB * SLICES_D, 512, 0, stream>>>(SC, curC, P, stride);
    finalize_deg<<<(N + 255) / 256, 256, 0, stream>>>(P, x, dinv, u, N, stride);
    const int half = NB * SLICES;
    hist_gather_both<<<2 * half, 512, 0, stream>>>(SC, SR, curC, curR, u, dinv,
                                                   Ps, Pw, stride, half);
    fused_node<<<(N + 255) / 256, 256, 0, stream>>>(Ps, Pw, dinv, x, W1, b1,
                                                    tslot, N, stride,
                                                    W2, b2, out, OUT,
                                                    1.0f / (float)N, cnt);
}

// Round 7
// 189.947 us; speedup vs baseline: 1.1204x; 1.0420x over previous
//
#include <hip/hip_runtime.h>
#include <math.h>

// GCN collapsed to scalar-per-node form:
//   deg[c] = 1 + #{col==c};  dinv = rsqrt(deg);  u = dinv*x
//   s_raw[c] = sum_{col=c} u[row];  sc = dinv*s_raw + dinv^2*x
//   w_raw[r] = sum_{row=r} dinv[col];  w = dinv*(w_raw + dinv)
//   total[k] = sum_i w[i]*relu(sc[i]*W1[k]+b1[k]);  out = total/N @ W2 + b2
//
// R12: scatter's 46us wall identified as the bucket-reservation atomics:
// curC[32]/curR[32] each sit in ONE 128B L2 line; 1563 blocks x 64 lane
// rtn-RMWs = 100K atomics serialized through 2 lines (~few cy each ~= the
// whole 46us; explains why doubling occupancy R11 didn't help). Fix:
// stride counters to one per 256B line (curX[b*CSTR], CSTR=64 ints) ->
// 32 parallel L2 lines. Also: revert hist path to R9-measured config
// (SLICES=12, S_D=24, 256-thread blocks) -- R11's slice halving cost
// ~16us in coverage/imbalance for a 10MB (~3us) traffic saving.
// Kept: EPT=4 scatter (54% occ now useful), count-semantics counters,
// tslot de-contended accumulator, fence-free ticket epilogue.

constexpr int BKT_BITS = 12;
constexpr int BKT_SIZE = 1 << BKT_BITS;   // 4096
constexpr int NBMAX    = 32;
constexpr int CSTR     = 64;              // ints between counters (256B line each)
constexpr int CAP      = 67584;           // per-bucket region capacity (mean+8sigma)
constexpr int SLICES   = 12;              // gather-hist slices per bucket
constexpr int SLICES_D = 24;              // deg-hist slices per bucket
constexpr int EPT      = 4;               // edges per thread in scatter
constexpr int NSLOT    = 32;              // accumulator slot-groups

__global__ void init_misc(int* __restrict__ curC, int* __restrict__ curR,
                          float* __restrict__ tslot, unsigned* __restrict__ cnt) {
    int t = threadIdx.x;
    if (t < NBMAX) { curC[t * CSTR] = 0; curR[t * CSTR] = 0; }
    for (int j = t; j < NSLOT * 128; j += 256) tslot[j] = 0.0f;
    if (t == 0) *cnt = 0u;
}

// One tile (1024 edges) per block. Single return-atomic per edge-side gives
// the within-tile slot; global range reserved once per bucket after sync
// (strided counters: 32 parallel L2 lines, no same-line serialization).
__global__ void scatter_edges(const int* __restrict__ row, const int* __restrict__ col,
                              int* __restrict__ SC, int* __restrict__ SR,
                              int* __restrict__ curC, int* __restrict__ curR, int E) {
    __shared__ int hC[NBMAX], hR[NBMAX], bC[NBMAX], bR[NBMAX];
    const int TILE = blockDim.x * EPT;
    const int myBase = blockIdx.x * TILE + threadIdx.x * EPT;
    int r[EPT], c[EPT];
    if (myBase + EPT <= E) {
        int4 r0 = *reinterpret_cast<const int4*>(row + myBase);
        int4 c0 = *reinterpret_cast<const int4*>(col + myBase);
        r[0]=r0.x; r[1]=r0.y; r[2]=r0.z; r[3]=r0.w;
        c[0]=c0.x; c[1]=c0.y; c[2]=c0.z; c[3]=c0.w;
    } else {
#pragma unroll
        for (int j = 0; j < EPT; ++j) {
            int e = myBase + j;
            r[j] = (e < E) ? row[e] : -1;
            c[j] = (e < E) ? col[e] : -1;
        }
    }
    if (threadIdx.x < NBMAX) { hC[threadIdx.x] = 0; hR[threadIdx.x] = 0; }
    __syncthreads();
    int offC[EPT], offR[EPT];
#pragma unroll
    for (int j = 0; j < EPT; ++j) {
        if (r[j] >= 0) {
            offC[j] = atomicAdd(&hC[c[j] >> BKT_BITS], 1);   // rtn-atomic: slot
            offR[j] = atomicAdd(&hR[r[j] >> BKT_BITS], 1);
        }
    }
    __syncthreads();
    if (threadIdx.x < NBMAX) {
        bC[threadIdx.x] = atomicAdd(&curC[threadIdx.x * CSTR], hC[threadIdx.x]);
        bR[threadIdx.x] = atomicAdd(&curR[threadIdx.x * CSTR], hR[threadIdx.x]);
    }
    __syncthreads();
#pragma unroll
    for (int j = 0; j < EPT; ++j) {
        if (r[j] >= 0) {
            int kb = c[j] >> BKT_BITS;
            int idx = kb * CAP + bC[kb] + offC[j];
            if (idx < (kb + 1) * CAP)           // overflow clamp (8-sigma margin)
                SC[idx] = ((c[j] & (BKT_SIZE - 1)) << 17) | r[j];
            int kb2 = r[j] >> BKT_BITS;
            int idx2 = kb2 * CAP + bR[kb2] + offR[j];
            if (idx2 < (kb2 + 1) * CAP)
                SR[idx2] = ((r[j] & (BKT_SIZE - 1)) << 17) | c[j];
        }
    }
}

__global__ void hist_deg(const int* __restrict__ SC, const int* __restrict__ cur,
                         float* __restrict__ P, int stride) {
    __shared__ float bins[BKT_SIZE];
    const int b = blockIdx.x / SLICES_D, s = blockIdx.x % SLICES_D;
    const int base = b * CAP;
    int len = cur[b * CSTR];
    len = len < CAP ? len : CAP;
    const int lo = base + (int)((long long)len * s / SLICES_D);
    const int hi = base + (int)((long long)len * (s + 1) / SLICES_D);
    for (int i = threadIdx.x; i < BKT_SIZE; i += blockDim.x) bins[i] = 0.0f;
    __syncthreads();
    for (int e = lo + threadIdx.x; e < hi; e += blockDim.x)
        atomicAdd(&bins[SC[e] >> 17], 1.0f);
    __syncthreads();
    float* dst = P + (size_t)s * stride + b * BKT_SIZE;
    for (int i = threadIdx.x; i < BKT_SIZE; i += blockDim.x) dst[i] = bins[i];
}

__global__ void finalize_deg(const float* __restrict__ Pd, const float* __restrict__ x,
                             float* __restrict__ dinv, float* __restrict__ u,
                             int N, int stride) {
    int i = blockIdx.x * blockDim.x + threadIdx.x;
    if (i >= N) return;
    float d = 1.0f;  // self loop
    for (int s = 0; s < SLICES_D; ++s) d += Pd[(size_t)s * stride + i];
    float di = rsqrtf(d);
    dinv[i] = di;
    u[i] = di * x[i];
}

// first half of grid: s-hist over SC gathering u; second half: w-hist over SR
// gathering dinv. Branch is block-uniform.
__global__ void hist_gather_both(const int* __restrict__ SC, const int* __restrict__ SR,
                                 const int* __restrict__ curC, const int* __restrict__ curR,
                                 const float* __restrict__ u, const float* __restrict__ dinv,
                                 float* __restrict__ Ps, float* __restrict__ Pw,
                                 int stride, int half) {
    __shared__ float bins[BKT_SIZE];
    const bool isW = blockIdx.x >= half;
    const int id = isW ? blockIdx.x - half : blockIdx.x;
    const int* S = isW ? SR : SC;
    const int* cur = isW ? curR : curC;
    const float* val = isW ? dinv : u;
    float* P = isW ? Pw : Ps;
    const int b = id / SLICES, s = id % SLICES;
    const int base = b * CAP;
    int len = cur[b * CSTR];
    len = len < CAP ? len : CAP;
    const int lo = base + (int)((long long)len * s / SLICES);
    const int hi = base + (int)((long long)len * (s + 1) / SLICES);
    for (int i = threadIdx.x; i < BKT_SIZE; i += blockDim.x) bins[i] = 0.0f;
    __syncthreads();
    for (int e = lo + threadIdx.x; e < hi; e += blockDim.x) {
        int v = S[e];
        atomicAdd(&bins[v >> 17], val[v & 0x1FFFF]);
    }
    __syncthreads();
    float* dst = P + (size_t)s * stride + b * BKT_SIZE;
    for (int i = threadIdx.x; i < BKT_SIZE; i += blockDim.x) dst[i] = bins[i];
}

// Fused: finalize sc/w for 256 nodes, per-block k-phase from LDS broadcasts,
// atomic-accumulate into tslot[blockIdx&31][128]; LAST block (device-scope
// ticket) sums the 32x128 slots and runs the 128x400 W2 epilogue inline.
__global__ void fused_node(const float* __restrict__ Ps, const float* __restrict__ Pw,
                           const float* __restrict__ dinv, const float* __restrict__ x,
                           const float* __restrict__ W1, const float* __restrict__ b1,
                           float* __restrict__ tslot, int N, int stride,
                           const float* __restrict__ W2, const float* __restrict__ b2,
                           float* __restrict__ out, int OUT, float invN,
                           unsigned* __restrict__ cnt) {
    __shared__ float scs[256];
    __shared__ float ws[256];
    __shared__ float red[256];
    __shared__ unsigned lastFlag;
    const int tid = threadIdx.x;
    const int i = blockIdx.x * 256 + tid;
    float scv = 0.0f, wv = 0.0f;
    if (i < N) {
        float sr = 0.0f, wr = 0.0f;
        for (int s = 0; s < SLICES; ++s) {
            sr += Ps[(size_t)s * stride + i];
            wr += Pw[(size_t)s * stride + i];
        }
        float di = dinv[i];
        scv = di * sr + di * di * x[i];
        wv  = di * (wr + di);
    }
    scs[tid] = scv;
    ws[tid]  = wv;     // 0 for i>=N -> zero contribution
    __syncthreads();
    const int k = tid & 127;
    const int base = (tid >> 7) * 128;
    const float w1k = W1[k];
    const float b1k = b1[k];
    float acc = 0.0f;
#pragma unroll 4
    for (int j = 0; j < 128; ++j) {
        float h = scs[base + j] * w1k + b1k;
        h = h > 0.0f ? h : 0.0f;
        acc += ws[base + j] * h;
    }
    red[tid] = acc;
    __syncthreads();
    if (tid < 128)
        atomicAdd(&tslot[(blockIdx.x & (NSLOT - 1)) * 128 + k],
                  red[tid] + red[tid + 128]);
    // __syncthreads below drains vmcnt -> this block's tslot atomics are
    // acked at the coherence point before its ticket increments. No fence:
    // all cross-block traffic here is device-scope atomics.
    __syncthreads();
    if (tid == 0)
        lastFlag = (atomicAdd(cnt, 1u) == (unsigned)(gridDim.x - 1)) ? 1u : 0u;
    __syncthreads();
    if (lastFlag) {
        __shared__ float tv[128];
        if (tid < 128) {
            float s = 0.0f;
#pragma unroll
            for (int g = 0; g < NSLOT; ++g)
                s += atomicAdd(&tslot[g * 128 + tid], 0.0f);  // coherent reads
            tv[tid] = s * invN;
        }
        __syncthreads();
        for (int d = tid; d < OUT; d += 256) {
            float a = b2[d];
#pragma unroll 4
            for (int kk = 0; kk < 128; ++kk) a += tv[kk] * W2[kk * OUT + d];
            out[d] = a;
        }
    }
}

extern "C" void kernel_launch(void* const* d_in, const int* in_sizes, int n_in,
                              void* d_out, int out_size, void* d_ws, size_t ws_size,
                              hipStream_t stream) {
    const float* x          = (const float*)d_in[0];
    const int*   edge_index = (const int*)  d_in[1];
    const float* W1         = (const float*)d_in[2];
    const float* b1         = (const float*)d_in[3];
    const float* W2         = (const float*)d_in[4];
    const float* b2         = (const float*)d_in[5];
    float* out = (float*)d_out;

    const int N   = in_sizes[0];      // 100000
    const int E   = in_sizes[1] / 2;  // 1600000
    const int OUT = in_sizes[5];      // 400

    const int* row = edge_index;
    const int* col = edge_index + E;

    const int NB = (N + BKT_SIZE - 1) >> BKT_BITS;   // 25
    const int stride = NB * BKT_SIZE;                // 102400

    // workspace layout
    char* p = (char*)d_ws;
    float* dinv  = (float*)p; p += (size_t)N * 4;
    float* u     = (float*)p; p += (size_t)N * 4;
    float* tslot = (float*)p; p += (size_t)NSLOT * 128 * 4;   // 16 KB
    int*   ints  = (int*)p;   p += (size_t)(2 * NBMAX * CSTR + CSTR) * 4; // strided ctrs + cnt
    int*   SC    = (int*)p;   p += (size_t)NB * CAP * 4;
    int*   SR    = (int*)p;   p += (size_t)NB * CAP * 4;
    float* P     = (float*)p;                        // max(SLICES_D, 2*SLICES)*stride
    float* Ps    = P;                                // aliases Pd (sequential phases)
    float* Pw    = P + (size_t)SLICES * stride;

    int* curC = ints;                                // counters at i*CSTR
    int* curR = ints + NBMAX * CSTR;
    unsigned* cnt = (unsigned*)(ints + 2 * NBMAX * CSTR);

    const int TILE   = 256 * EPT;
    const int nTiles = (E + TILE - 1) / TILE;        // 1563 -> 6 blocks/CU

    init_misc<<<1, 256, 0, stream>>>(curC, curR, tslot, cnt);
    scatter_edges<<<nTiles, 256, 0, stream>>>(row, col, SC, SR, curC, curR, E);
    hist_deg<<<NB * SLICES_D, 256, 0, stream>>>(SC, curC, P, stride);
    finalize_deg<<<(N + 255) / 256, 256, 0, stream>>>(P, x, dinv, u, N, stride);
    const int half = NB * SLICES;
    hist_gather_both<<<2 * half, 256, 0, stream>>>(SC, SR, curC, curR, u, dinv,
                                                   Ps, Pw, stride, half);
    fused_node<<<(N + 255) / 256, 256, 0, stream>>>(Ps, Pw, dinv, x, W1, b1,
                                                    tslot, N, stride,
                                                    W2, b2, out, OUT,
                                                    1.0f / (float)N, cnt);
}